// Round 7
// baseline (116.770 us; speedup 1.0000x reference)
//
#include <hip/hip_runtime.h>
#include <hip/hip_bf16.h>

#define NN 512
#define FD 256
#define FI 128

// workspace layout (float offsets)
#define OFF_AIN   0          // 2048*128  A_in' = We1@(Wi x + bi + bp) + be1
#define OFF_D     262144     // 2048*128  D = -We1@(Wo x + bo)
#define OFF_COEF  524288     // 32*16     per-gq packed {w0[4], w1[4], v[4], pad}
#define OFF_PART  524800     // 512*64    per-(b,jt,ir) partial maxes
// total 557568 floats = 2.13 MB (safe: <= 3.41 MB proven envelope)

// gelu(x) ~= x * sigmoid(1.5957691216*(x + 0.044715 x^3)); log2e folded in
__device__ __forceinline__ float fast_gelu(float x) {
    float x2 = x * x;
    float s  = __fmaf_rn(0.10294325f, x2, 2.3022083f);   // coeffs * log2(e)
    float zs = x * s;
    float e  = __builtin_amdgcn_exp2f(zs);               // v_exp_f32: 2^x
    float r  = __builtin_amdgcn_rcpf(e + 1.0f);
    return __fmaf_rn(-x, r, x);
}

// ---- kernel 1: fused node projections (h = W x + b, then A/D = We1 h) -------
__global__ __launch_bounds__(256) void node_fused_kernel(
    const float* __restrict__ x,
    const float* __restrict__ Wp,  const float* __restrict__ bp,
    const float* __restrict__ Wi,  const float* __restrict__ bi,
    const float* __restrict__ Wo,  const float* __restrict__ bo,
    const float* __restrict__ We1, const float* __restrict__ be1,
    const float* __restrict__ We2, float* ws)
{
    __shared__ __align__(16) float xs[4][FD];        // 4 KB
    __shared__ __align__(16) float hbuf[2][4][FI];   // 4 KB
    int t  = threadIdx.x;
    int nb = blockIdx.x * 4;                         // 512 blocks * 4 nodes

    // block 0 also produces the packed coef table (edge-kernel constants)
    if (blockIdx.x == 0 && t < FI) {
        const float* wr = We1 + t * FI;
        float a0 = 0.f, a1 = 0.f;
        for (int f = 0; f < FI; ++f) {
            float w = wr[f];
            a0 = __fmaf_rn(w, Wp[f * 2 + 0], a0);
            a1 = __fmaf_rn(w, Wp[f * 2 + 1], a1);
        }
        int gq = t >> 2, k = t & 3;
        ws[OFF_COEF + gq * 16 + k]     = a0;
        ws[OFF_COEF + gq * 16 + 4 + k] = a1;
        ws[OFF_COEF + gq * 16 + 8 + k] = We2[t];
    }

    ((float4*)xs)[t] = ((const float4*)(x + nb * FD))[t];
    __syncthreads();

    // stage B: h[io][n][f] = W_io[f,:] . x[n,:] + bias
    int io = t >> 7, f = t & 127;
    const float* Wrow = (io ? Wo : Wi) + f * FD;
    float bias = io ? bo[f] : (bi[f] + bp[f]);
    float acc[4] = {0.f, 0.f, 0.f, 0.f};
    for (int d4 = 0; d4 < FD / 4; ++d4) {
        float4 wv = ((const float4*)Wrow)[d4];
        #pragma unroll
        for (int n = 0; n < 4; ++n) {
            float4 xv = ((const float4*)&xs[n][0])[d4];
            acc[n] = __fmaf_rn(wv.x, xv.x, acc[n]);
            acc[n] = __fmaf_rn(wv.y, xv.y, acc[n]);
            acc[n] = __fmaf_rn(wv.z, xv.z, acc[n]);
            acc[n] = __fmaf_rn(wv.w, xv.w, acc[n]);
        }
    }
    #pragma unroll
    for (int n = 0; n < 4; ++n) hbuf[io][n][f] = acc[n] + bias;
    __syncthreads();

    // stage C: A_in[n][g] = We1[g,:].h_in[n,:] + be1[g];  D[n][g] = -We1[g,:].h_out[n,:]
    int g = f;
    const float* Erow = We1 + g * FI;
    float acc2[4] = {0.f, 0.f, 0.f, 0.f};
    for (int f4 = 0; f4 < FI / 4; ++f4) {
        float4 ev = ((const float4*)Erow)[f4];
        #pragma unroll
        for (int n = 0; n < 4; ++n) {
            float4 hv = ((const float4*)&hbuf[io][n][0])[f4];
            acc2[n] = __fmaf_rn(ev.x, hv.x, acc2[n]);
            acc2[n] = __fmaf_rn(ev.y, hv.y, acc2[n]);
            acc2[n] = __fmaf_rn(ev.z, hv.z, acc2[n]);
            acc2[n] = __fmaf_rn(ev.w, hv.w, acc2[n]);
        }
    }
    if (io == 0) {
        float bg = be1[g];
        #pragma unroll
        for (int n = 0; n < 4; ++n)
            ws[OFF_AIN + (nb + n) * FI + g] = acc2[n] + bg;
    } else {
        #pragma unroll
        for (int n = 0; n < 4; ++n)
            ws[OFF_D + (nb + n) * FI + g] = -acc2[n];
    }
}

// ---- kernel 2: edge MLP on ACTIVE edges only (in-kernel compaction) ---------
// 512 blocks = 4b * 8jt * 16ir; tile = 32 i-rows x 64 j-cols; 512 threads
__global__ __launch_bounds__(512) void edge_kernel(
    const float* __restrict__ pos, const float* __restrict__ sup,
    const float* __restrict__ Ain, const float* __restrict__ Dmat,
    const float* __restrict__ coef, const float* __restrict__ be2p,
    float* __restrict__ part)
{
    __shared__ __align__(16) float sD[64 * 128];   // 32 KB, swizzle (r&31)<<2
    __shared__ __align__(16) float sA[32 * 128];   // 16 KB, swizzle (r&31)<<2
    __shared__ __align__(16) float sC[512];        // 2 KB
    __shared__ unsigned short sList[2048];         // 4 KB active-edge list
    __shared__ int smax[64];                       // per-j col max (float bits)
    __shared__ int scnt;

    int tile = blockIdx.x;
    int ir = tile & 15, jt = (tile >> 4) & 7, b = tile >> 7;   // 16*8*4 = 512
    int tid = threadIdx.x;
    int lane = tid & 63;

    // stage D (64 j-rows): word = r*128 + (c ^ ((r&31)<<2))  [bijective in-row]
    const float4* Dg4 = (const float4*)(Dmat + (b * NN + jt * 64) * FI);
    #pragma unroll
    for (int k = 0; k < 4; ++k) {
        int s = tid + k * 512;
        float4 v = Dg4[s];
        int r = s >> 5, c = (s & 31) * 4;
        *(float4*)(sD + r * 128 + (c ^ ((r & 31) << 2))) = v;
    }
    // stage A (32 i-rows)
    const float4* Ag4 = (const float4*)(Ain + (b * NN + ir * 32) * FI);
    #pragma unroll
    for (int k = 0; k < 2; ++k) {
        int s = tid + k * 512;
        float4 v = Ag4[s];
        int r = s >> 5, c = (s & 31) * 4;
        *(float4*)(sA + r * 128 + (c ^ ((r & 31) << 2))) = v;
    }
    if (tid < 128) ((float4*)sC)[tid] = ((const float4*)coef)[tid];
    if (tid < 64) smax[tid] = 0;   // 0.0f == exact value of suppressed edges
    if (tid == 0) scnt = 0;
    __syncthreads();

    // compaction: round k handles i-row (k*8 + wave), 64 j's per wave
    const float* S = sup + (size_t)(b * NN + ir * 32) * NN + jt * 64;
    #pragma unroll
    for (int k = 0; k < 4; ++k) {
        int s = tid + k * 512;
        int i_l = s >> 6, j_l = s & 63;
        bool act = (S[i_l * NN + j_l] != 0.f);
        unsigned long long mask = __ballot(act);
        int wbase = 0;
        if (lane == 0 && mask) wbase = atomicAdd(&scnt, (int)__popcll(mask));
        wbase = __shfl(wbase, 0);
        if (act) {
            int prefix = (int)__popcll(mask & ((1ull << lane) - 1ull));
            sList[wbase + prefix] = (unsigned short)s;
        }
    }
    __syncthreads();

    int cnt = scnt;
    float be2 = *be2p;
    const float2* pos2 = (const float2*)pos;

    for (int r = tid; r < cnt; r += 512) {
        int e = (int)sList[r];
        int i_l = e >> 6, j_l = e & 63;
        float2 pp = pos2[(size_t)(b * NN + ir * 32 + i_l) * NN + jt * 64 + j_l];
        const float* Ar = sA + i_l * 128;
        const float* Dr = sD + j_l * 128;
        int aswz = i_l << 2;           // i_l < 32
        int dswz = (j_l & 31) << 2;
        float z = 0.f;
        #pragma unroll
        for (int gq = 0; gq < 32; ++gq) {
            float4 a  = *(const float4*)(Ar + ((gq * 4) ^ aswz));
            float4 d  = *(const float4*)(Dr + ((gq * 4) ^ dswz));
            float4 w0 = *(const float4*)(sC + gq * 16);
            float4 w1 = *(const float4*)(sC + gq * 16 + 4);
            float4 vv = *(const float4*)(sC + gq * 16 + 8);
            float y0 = __fmaf_rn(w1.x, pp.y, __fmaf_rn(w0.x, pp.x, a.x + d.x));
            float y1 = __fmaf_rn(w1.y, pp.y, __fmaf_rn(w0.y, pp.x, a.y + d.y));
            float y2 = __fmaf_rn(w1.z, pp.y, __fmaf_rn(w0.z, pp.x, a.z + d.z));
            float y3 = __fmaf_rn(w1.w, pp.y, __fmaf_rn(w0.w, pp.x, a.w + d.w));
            z = __fmaf_rn(vv.x, fast_gelu(y0), z);
            z = __fmaf_rn(vv.y, fast_gelu(y1), z);
            z = __fmaf_rn(vv.z, fast_gelu(y2), z);
            z = __fmaf_rn(vv.w, fast_gelu(y3), z);
        }
        // positive floats order-preserve as signed ints; negatives < 0 == init
        atomicMax(&smax[j_l], __float_as_int(z + be2));
    }
    __syncthreads();
    if (tid < 64)
        part[tile * 64 + tid] = __int_as_float(smax[tid]);
}

// ---- kernel 3: reduce 16 i-range partials + node FFN ------------------------
__global__ __launch_bounds__(256) void final_kernel(
    const float* __restrict__ Wn1, const float* __restrict__ bn1,
    const float* __restrict__ Wn2, const float* __restrict__ bn2,
    const float* __restrict__ part, float* __restrict__ out)
{
    __shared__ float red[8][17];
    __shared__ float nm[8];
    __shared__ __align__(16) float h1[8][FD];
    int nb = blockIdx.x * 8;                  // 256 blocks * 8 nodes
    int b  = nb >> 9;
    int j0 = nb & 511;
    int jt = j0 >> 6, jl0 = j0 & 63;
    int t = threadIdx.x;
    if (t < 128) {
        int k = t & 7, ir = t >> 3;           // ir in 0..15
        red[k][ir] = part[(((b << 7) | (jt << 4) | ir)) * 64 + jl0 + k];
    }
    __syncthreads();
    if (t < 8) {
        float m2 = red[t][0];
        #pragma unroll
        for (int q = 1; q < 16; ++q) m2 = fmaxf(m2, red[t][q]);
        nm[t] = m2;
    }
    __syncthreads();
    {
        float wv = Wn1[t];        // Wn1 shape [256,1]
        float bv = bn1[t];
        #pragma unroll
        for (int n = 0; n < 8; ++n)
            h1[n][t] = fmaxf(0.f, __fmaf_rn(nm[n], wv, bv));
    }
    __syncthreads();
    float acc[8] = {0.f,0.f,0.f,0.f,0.f,0.f,0.f,0.f};
    const float4* w2 = (const float4*)(Wn2 + t * FD);
    for (int d4 = 0; d4 < FD / 4; ++d4) {
        float4 wv = w2[d4];
        #pragma unroll
        for (int n = 0; n < 8; ++n) {
            float4 xv = ((const float4*)&h1[n][0])[d4];
            acc[n] = __fmaf_rn(wv.x, xv.x, acc[n]);
            acc[n] = __fmaf_rn(wv.y, xv.y, acc[n]);
            acc[n] = __fmaf_rn(wv.z, xv.z, acc[n]);
            acc[n] = __fmaf_rn(wv.w, xv.w, acc[n]);
        }
    }
    float bb = bn2[t];
    #pragma unroll
    for (int n = 0; n < 8; ++n)
        out[(size_t)(nb + n) * FD + t] = fmaxf(0.f, acc[n] + bb);
}

extern "C" void kernel_launch(void* const* d_in, const int* in_sizes, int n_in,
                              void* d_out, int out_size, void* d_ws, size_t ws_size,
                              hipStream_t stream) {
    (void)in_sizes; (void)n_in; (void)out_size; (void)ws_size;
    const float* node = (const float*)d_in[0];
    const float* sup  = (const float*)d_in[1];
    const float* pos  = (const float*)d_in[2];
    const float* Wp   = (const float*)d_in[3];
    const float* bp   = (const float*)d_in[4];
    const float* Wi   = (const float*)d_in[5];
    const float* bi   = (const float*)d_in[6];
    const float* Wo   = (const float*)d_in[7];
    const float* bo   = (const float*)d_in[8];
    const float* We1  = (const float*)d_in[9];
    const float* be1  = (const float*)d_in[10];
    const float* We2  = (const float*)d_in[11];
    const float* be2  = (const float*)d_in[12];
    const float* Wn1  = (const float*)d_in[13];
    const float* bn1  = (const float*)d_in[14];
    const float* Wn2  = (const float*)d_in[15];
    const float* bn2  = (const float*)d_in[16];
    float* ws  = (float*)d_ws;
    float* out = (float*)d_out;

    node_fused_kernel<<<512, 256, 0, stream>>>(node, Wp, bp, Wi, bi, Wo, bo,
                                               We1, be1, We2, ws);
    edge_kernel<<<512, 512, 0, stream>>>(pos, sup, ws + OFF_AIN, ws + OFF_D,
                                         ws + OFF_COEF, be2, ws + OFF_PART);
    final_kernel<<<256, 256, 0, stream>>>(Wn1, bn1, Wn2, bn2,
                                          ws + OFF_PART, out);
}

// Round 8
// 81.995 us; speedup vs baseline: 1.4241x; 1.4241x over previous
//
#include <hip/hip_runtime.h>
#include <hip/hip_bf16.h>

#define NN 512
#define FD 256
#define FI 128

// workspace layout (float offsets)
#define OFF_AIN   0          // 2048*128  A_in' = We1@(Wi x + bi + bp) + be1
#define OFF_D     262144     // 2048*128  D = -We1@(Wo x + bo)
#define OFF_COEF  524288     // 32*16     per-gq packed {w0[4], w1[4], v[4], pad}
#define OFF_PART  524800     // 512*64    per-(b,jt,ir) partial maxes
// total 557568 floats = 2.13 MB

// gelu(x) ~= x * sigmoid(1.5957691216*(x + 0.044715 x^3)); log2e folded in
__device__ __forceinline__ float fast_gelu(float x) {
    float x2 = x * x;
    float s  = __fmaf_rn(0.10294325f, x2, 2.3022083f);   // coeffs * log2(e)
    float zs = x * s;
    float e  = __builtin_amdgcn_exp2f(zs);               // v_exp_f32: 2^x
    float r  = __builtin_amdgcn_rcpf(e + 1.0f);
    return __fmaf_rn(-x, r, x);
}

// ---- kernel 1: fused node projections (h = W x + b, then A/D = We1 h) -------
__global__ __launch_bounds__(256) void node_fused_kernel(
    const float* __restrict__ x,
    const float* __restrict__ Wp,  const float* __restrict__ bp,
    const float* __restrict__ Wi,  const float* __restrict__ bi,
    const float* __restrict__ Wo,  const float* __restrict__ bo,
    const float* __restrict__ We1, const float* __restrict__ be1,
    const float* __restrict__ We2, float* ws)
{
    __shared__ __align__(16) float xs[4][FD];        // 4 KB
    __shared__ __align__(16) float hbuf[2][4][FI];   // 4 KB
    int t  = threadIdx.x;
    int nb = blockIdx.x * 4;                         // 512 blocks * 4 nodes

    // block 0 also produces the packed coef table (edge-kernel constants)
    if (blockIdx.x == 0 && t < FI) {
        const float* wr = We1 + t * FI;
        float a0 = 0.f, a1 = 0.f;
        for (int f = 0; f < FI; ++f) {
            float w = wr[f];
            a0 = __fmaf_rn(w, Wp[f * 2 + 0], a0);
            a1 = __fmaf_rn(w, Wp[f * 2 + 1], a1);
        }
        int gq = t >> 2, k = t & 3;
        ws[OFF_COEF + gq * 16 + k]     = a0;
        ws[OFF_COEF + gq * 16 + 4 + k] = a1;
        ws[OFF_COEF + gq * 16 + 8 + k] = We2[t];
    }

    ((float4*)xs)[t] = ((const float4*)(x + nb * FD))[t];
    __syncthreads();

    // stage B: h[io][n][f] = W_io[f,:] . x[n,:] + bias
    int io = t >> 7, f = t & 127;
    const float* Wrow = (io ? Wo : Wi) + f * FD;
    float bias = io ? bo[f] : (bi[f] + bp[f]);
    float acc[4] = {0.f, 0.f, 0.f, 0.f};
    for (int d4 = 0; d4 < FD / 4; ++d4) {
        float4 wv = ((const float4*)Wrow)[d4];
        #pragma unroll
        for (int n = 0; n < 4; ++n) {
            float4 xv = ((const float4*)&xs[n][0])[d4];
            acc[n] = __fmaf_rn(wv.x, xv.x, acc[n]);
            acc[n] = __fmaf_rn(wv.y, xv.y, acc[n]);
            acc[n] = __fmaf_rn(wv.z, xv.z, acc[n]);
            acc[n] = __fmaf_rn(wv.w, xv.w, acc[n]);
        }
    }
    #pragma unroll
    for (int n = 0; n < 4; ++n) hbuf[io][n][f] = acc[n] + bias;
    __syncthreads();

    // stage C: A_in[n][g] = We1[g,:].h_in[n,:] + be1[g];  D[n][g] = -We1[g,:].h_out[n,:]
    int g = f;
    const float* Erow = We1 + g * FI;
    float acc2[4] = {0.f, 0.f, 0.f, 0.f};
    for (int f4 = 0; f4 < FI / 4; ++f4) {
        float4 ev = ((const float4*)Erow)[f4];
        #pragma unroll
        for (int n = 0; n < 4; ++n) {
            float4 hv = ((const float4*)&hbuf[io][n][0])[f4];
            acc2[n] = __fmaf_rn(ev.x, hv.x, acc2[n]);
            acc2[n] = __fmaf_rn(ev.y, hv.y, acc2[n]);
            acc2[n] = __fmaf_rn(ev.z, hv.z, acc2[n]);
            acc2[n] = __fmaf_rn(ev.w, hv.w, acc2[n]);
        }
    }
    if (io == 0) {
        float bg = be1[g];
        #pragma unroll
        for (int n = 0; n < 4; ++n)
            ws[OFF_AIN + (nb + n) * FI + g] = acc2[n] + bg;
    } else {
        #pragma unroll
        for (int n = 0; n < 4; ++n)
            ws[OFF_D + (nb + n) * FI + g] = -acc2[n];
    }
}

// ---- kernel 2: edge MLP on ACTIVE edges only (in-kernel compaction) ---------
// 512 blocks = 4b * 8jt * 16ir; tile = 32 i-rows x 64 j-cols; 512 threads
__global__ __launch_bounds__(512) void edge_kernel(
    const float* __restrict__ pos, const float* __restrict__ sup,
    const float* __restrict__ Ain, const float* __restrict__ Dmat,
    const float* __restrict__ coef, const float* __restrict__ be2p,
    float* __restrict__ part)
{
    __shared__ __align__(16) float sD[64 * 128];   // 32 KB, swizzle (r&31)<<2
    __shared__ __align__(16) float sA[32 * 128];   // 16 KB, swizzle (r&31)<<2
    __shared__ __align__(16) float sC[512];        // 2 KB
    __shared__ unsigned short sList[2048];         // 4 KB active-edge list
    __shared__ int smax[64];                       // per-j col max (float bits)
    __shared__ int scnt;

    int tile = blockIdx.x;
    int ir = tile & 15, jt = (tile >> 4) & 7, b = tile >> 7;   // 16*8*4 = 512
    int tid = threadIdx.x;
    int lane = tid & 63;

    // stage D (64 j-rows): word = r*128 + (c ^ ((r&31)<<2))  [bijective in-row]
    const float4* Dg4 = (const float4*)(Dmat + (b * NN + jt * 64) * FI);
    #pragma unroll
    for (int k = 0; k < 4; ++k) {
        int s = tid + k * 512;
        float4 v = Dg4[s];
        int r = s >> 5, c = (s & 31) * 4;
        *(float4*)(sD + r * 128 + (c ^ ((r & 31) << 2))) = v;
    }
    // stage A (32 i-rows)
    const float4* Ag4 = (const float4*)(Ain + (b * NN + ir * 32) * FI);
    #pragma unroll
    for (int k = 0; k < 2; ++k) {
        int s = tid + k * 512;
        float4 v = Ag4[s];
        int r = s >> 5, c = (s & 31) * 4;
        *(float4*)(sA + r * 128 + (c ^ ((r & 31) << 2))) = v;
    }
    if (tid < 128) ((float4*)sC)[tid] = ((const float4*)coef)[tid];
    if (tid < 64) smax[tid] = 0;   // 0.0f == exact value of suppressed edges
    if (tid == 0) scnt = 0;
    __syncthreads();

    // compaction: each wave's 64 entries stay within one i-row (j-contiguous)
    const float* S = sup + (size_t)(b * NN + ir * 32) * NN + jt * 64;
    #pragma unroll
    for (int k = 0; k < 4; ++k) {
        int s = tid + k * 512;
        int i_l = s >> 6, j_l = s & 63;
        bool act = (S[i_l * NN + j_l] != 0.f);
        unsigned long long mask = __ballot(act);
        int wbase = 0;
        if (lane == 0 && mask) wbase = atomicAdd(&scnt, (int)__popcll(mask));
        wbase = __shfl(wbase, 0);
        if (act) {
            int prefix = (int)__popcll(mask & ((1ull << lane) - 1ull));
            sList[wbase + prefix] = (unsigned short)s;
        }
    }
    __syncthreads();

    int cnt = scnt;
    float be2 = *be2p;
    const float2* pos2 = (const float2*)pos;

    for (int r = tid; r < cnt; r += 512) {
        int e = (int)sList[r];
        int i_l = e >> 6, j_l = e & 63;
        float2 pp = pos2[(size_t)(b * NN + ir * 32 + i_l) * NN + jt * 64 + j_l];
        const float* Ar = sA + i_l * 128;
        const float* Dr = sD + j_l * 128;
        int aswz = i_l << 2;           // i_l < 32
        int dswz = (j_l & 31) << 2;
        float z = 0.f;
        #pragma unroll 4
        for (int gq = 0; gq < 32; ++gq) {
            float4 a  = *(const float4*)(Ar + ((gq * 4) ^ aswz));
            float4 d  = *(const float4*)(Dr + ((gq * 4) ^ dswz));
            float4 w0 = *(const float4*)(sC + gq * 16);
            float4 w1 = *(const float4*)(sC + gq * 16 + 4);
            float4 vv = *(const float4*)(sC + gq * 16 + 8);
            float y0 = __fmaf_rn(w1.x, pp.y, __fmaf_rn(w0.x, pp.x, a.x + d.x));
            float y1 = __fmaf_rn(w1.y, pp.y, __fmaf_rn(w0.y, pp.x, a.y + d.y));
            float y2 = __fmaf_rn(w1.z, pp.y, __fmaf_rn(w0.z, pp.x, a.z + d.z));
            float y3 = __fmaf_rn(w1.w, pp.y, __fmaf_rn(w0.w, pp.x, a.w + d.w));
            z = __fmaf_rn(vv.x, fast_gelu(y0), z);
            z = __fmaf_rn(vv.y, fast_gelu(y1), z);
            z = __fmaf_rn(vv.z, fast_gelu(y2), z);
            z = __fmaf_rn(vv.w, fast_gelu(y3), z);
        }
        // positive floats order-preserve as signed ints; negatives < 0 == init
        atomicMax(&smax[j_l], __float_as_int(z + be2));
    }
    __syncthreads();
    if (tid < 64)
        part[tile * 64 + tid] = __int_as_float(smax[tid]);
}

// ---- kernel 3: reduce 16 i-range partials + node FFN ------------------------
__global__ __launch_bounds__(256) void final_kernel(
    const float* __restrict__ Wn1, const float* __restrict__ bn1,
    const float* __restrict__ Wn2, const float* __restrict__ bn2,
    const float* __restrict__ part, float* __restrict__ out)
{
    __shared__ float red[8][17];
    __shared__ float nm[8];
    __shared__ __align__(16) float h1[8][FD];
    int nb = blockIdx.x * 8;                  // 256 blocks * 8 nodes
    int b  = nb >> 9;
    int j0 = nb & 511;
    int jt = j0 >> 6, jl0 = j0 & 63;
    int t = threadIdx.x;
    if (t < 128) {
        int k = t & 7, ir = t >> 3;           // ir in 0..15
        red[k][ir] = part[(((b << 7) | (jt << 4) | ir)) * 64 + jl0 + k];
    }
    __syncthreads();
    if (t < 8) {
        float m2 = red[t][0];
        #pragma unroll
        for (int q = 1; q < 16; ++q) m2 = fmaxf(m2, red[t][q]);
        nm[t] = m2;
    }
    __syncthreads();
    {
        float wv = Wn1[t];        // Wn1 shape [256,1]
        float bv = bn1[t];
        #pragma unroll
        for (int n = 0; n < 8; ++n)
            h1[n][t] = fmaxf(0.f, __fmaf_rn(nm[n], wv, bv));
    }
    __syncthreads();
    float acc[8] = {0.f,0.f,0.f,0.f,0.f,0.f,0.f,0.f};
    const float4* w2 = (const float4*)(Wn2 + t * FD);
    for (int d4 = 0; d4 < FD / 4; ++d4) {
        float4 wv = w2[d4];
        #pragma unroll
        for (int n = 0; n < 8; ++n) {
            float4 xv = ((const float4*)&h1[n][0])[d4];
            acc[n] = __fmaf_rn(wv.x, xv.x, acc[n]);
            acc[n] = __fmaf_rn(wv.y, xv.y, acc[n]);
            acc[n] = __fmaf_rn(wv.z, xv.z, acc[n]);
            acc[n] = __fmaf_rn(wv.w, xv.w, acc[n]);
        }
    }
    float bb = bn2[t];
    #pragma unroll
    for (int n = 0; n < 8; ++n)
        out[(size_t)(nb + n) * FD + t] = fmaxf(0.f, acc[n] + bb);
}

extern "C" void kernel_launch(void* const* d_in, const int* in_sizes, int n_in,
                              void* d_out, int out_size, void* d_ws, size_t ws_size,
                              hipStream_t stream) {
    (void)in_sizes; (void)n_in; (void)out_size; (void)ws_size;
    const float* node = (const float*)d_in[0];
    const float* sup  = (const float*)d_in[1];
    const float* pos  = (const float*)d_in[2];
    const float* Wp   = (const float*)d_in[3];
    const float* bp   = (const float*)d_in[4];
    const float* Wi   = (const float*)d_in[5];
    const float* bi   = (const float*)d_in[6];
    const float* Wo   = (const float*)d_in[7];
    const float* bo   = (const float*)d_in[8];
    const float* We1  = (const float*)d_in[9];
    const float* be1  = (const float*)d_in[10];
    const float* We2  = (const float*)d_in[11];
    const float* be2  = (const float*)d_in[12];
    const float* Wn1  = (const float*)d_in[13];
    const float* bn1  = (const float*)d_in[14];
    const float* Wn2  = (const float*)d_in[15];
    const float* bn2  = (const float*)d_in[16];
    float* ws  = (float*)d_ws;
    float* out = (float*)d_out;

    node_fused_kernel<<<512, 256, 0, stream>>>(node, Wp, bp, Wi, bi, Wo, bo,
                                               We1, be1, We2, ws);
    edge_kernel<<<512, 512, 0, stream>>>(pos, sup, ws + OFF_AIN, ws + OFF_D,
                                         ws + OFF_COEF, be2, ws + OFF_PART);
    final_kernel<<<256, 256, 0, stream>>>(Wn1, bn1, Wn2, bn2,
                                          ws + OFF_PART, out);
}

// Round 9
// 78.105 us; speedup vs baseline: 1.4950x; 1.0498x over previous
//
#include <hip/hip_runtime.h>
#include <hip/hip_bf16.h>

#define NN 512
#define FD 256
#define FI 128

// workspace layout (float offsets)
#define OFF_AIN   0          // 2048*128  A_in' = We1@(Wi x + bi + bp) + be1
#define OFF_D     262144     // 2048*128  D = -We1@(Wo x + bo)
#define OFF_COEF  524288     // 32*16     per-gq packed {w0[4], w1[4], v[4], pad}
#define OFF_PART  524800     // 1024*32   per-(b,jt,ir) partial maxes
// total 557568 floats = 2.13 MB

// gelu(x) ~= x * sigmoid(1.5957691216*(x + 0.044715 x^3)); log2e folded in
__device__ __forceinline__ float fast_gelu(float x) {
    float x2 = x * x;
    float s  = __fmaf_rn(0.10294325f, x2, 2.3022083f);   // coeffs * log2(e)
    float zs = x * s;
    float e  = __builtin_amdgcn_exp2f(zs);               // v_exp_f32: 2^x
    float r  = __builtin_amdgcn_rcpf(e + 1.0f);
    return __fmaf_rn(-x, r, x);
}

// ---- kernel 1: fused node projections (h = W x + b, then A/D = We1 h) -------
__global__ __launch_bounds__(256) void node_fused_kernel(
    const float* __restrict__ x,
    const float* __restrict__ Wp,  const float* __restrict__ bp,
    const float* __restrict__ Wi,  const float* __restrict__ bi,
    const float* __restrict__ Wo,  const float* __restrict__ bo,
    const float* __restrict__ We1, const float* __restrict__ be1,
    const float* __restrict__ We2, float* ws)
{
    __shared__ __align__(16) float xs[4][FD];        // 4 KB
    __shared__ __align__(16) float hbuf[2][4][FI];   // 4 KB
    int t  = threadIdx.x;
    int nb = blockIdx.x * 4;                         // 512 blocks * 4 nodes

    // block 0 also produces the packed coef table (edge-kernel constants)
    if (blockIdx.x == 0 && t < FI) {
        const float* wr = We1 + t * FI;
        float a0 = 0.f, a1 = 0.f;
        for (int f = 0; f < FI; ++f) {
            float w = wr[f];
            a0 = __fmaf_rn(w, Wp[f * 2 + 0], a0);
            a1 = __fmaf_rn(w, Wp[f * 2 + 1], a1);
        }
        int gq = t >> 2, k = t & 3;
        ws[OFF_COEF + gq * 16 + k]     = a0;
        ws[OFF_COEF + gq * 16 + 4 + k] = a1;
        ws[OFF_COEF + gq * 16 + 8 + k] = We2[t];
    }

    ((float4*)xs)[t] = ((const float4*)(x + nb * FD))[t];
    __syncthreads();

    // stage B: h[io][n][f] = W_io[f,:] . x[n,:] + bias
    int io = t >> 7, f = t & 127;
    const float* Wrow = (io ? Wo : Wi) + f * FD;
    float bias = io ? bo[f] : (bi[f] + bp[f]);
    float acc[4] = {0.f, 0.f, 0.f, 0.f};
    for (int d4 = 0; d4 < FD / 4; ++d4) {
        float4 wv = ((const float4*)Wrow)[d4];
        #pragma unroll
        for (int n = 0; n < 4; ++n) {
            float4 xv = ((const float4*)&xs[n][0])[d4];
            acc[n] = __fmaf_rn(wv.x, xv.x, acc[n]);
            acc[n] = __fmaf_rn(wv.y, xv.y, acc[n]);
            acc[n] = __fmaf_rn(wv.z, xv.z, acc[n]);
            acc[n] = __fmaf_rn(wv.w, xv.w, acc[n]);
        }
    }
    #pragma unroll
    for (int n = 0; n < 4; ++n) hbuf[io][n][f] = acc[n] + bias;
    __syncthreads();

    // stage C: A_in[n][g] = We1[g,:].h_in[n,:] + be1[g];  D[n][g] = -We1[g,:].h_out[n,:]
    int g = f;
    const float* Erow = We1 + g * FI;
    float acc2[4] = {0.f, 0.f, 0.f, 0.f};
    for (int f4 = 0; f4 < FI / 4; ++f4) {
        float4 ev = ((const float4*)Erow)[f4];
        #pragma unroll
        for (int n = 0; n < 4; ++n) {
            float4 hv = ((const float4*)&hbuf[io][n][0])[f4];
            acc2[n] = __fmaf_rn(ev.x, hv.x, acc2[n]);
            acc2[n] = __fmaf_rn(ev.y, hv.y, acc2[n]);
            acc2[n] = __fmaf_rn(ev.z, hv.z, acc2[n]);
            acc2[n] = __fmaf_rn(ev.w, hv.w, acc2[n]);
        }
    }
    if (io == 0) {
        float bg = be1[g];
        #pragma unroll
        for (int n = 0; n < 4; ++n)
            ws[OFF_AIN + (nb + n) * FI + g] = acc2[n] + bg;
    } else {
        #pragma unroll
        for (int n = 0; n < 4; ++n)
            ws[OFF_D + (nb + n) * FI + g] = -acc2[n];
    }
}

// ---- kernel 2: edge MLP on ACTIVE edges only (in-kernel compaction) ---------
// 1024 blocks = 4b * 16jt * 16ir; tile = 32 i-rows x 32 j-cols; 512 threads
__global__ __launch_bounds__(512, 8) void edge_kernel(
    const float* __restrict__ pos, const float* __restrict__ sup,
    const float* __restrict__ Ain, const float* __restrict__ Dmat,
    const float* __restrict__ coef, const float* __restrict__ be2p,
    float* __restrict__ part)
{
    __shared__ __align__(16) float sD[32 * 128];   // 16 KB, swizzle (r&31)<<2
    __shared__ __align__(16) float sA[32 * 128];   // 16 KB, swizzle (r&31)<<2
    __shared__ __align__(16) float sC[512];        // 2 KB
    __shared__ unsigned short sList[1024];         // 2 KB active-edge list
    __shared__ int smax[32];                       // per-j col max (float bits)
    __shared__ int scnt;                           // total ~36.2 KB -> 4 blk/CU

    int tile = blockIdx.x;
    int ir = tile & 15, jt = (tile >> 4) & 15, b = tile >> 8;  // 16*16*4 = 1024
    int tid = threadIdx.x;
    int lane = tid & 63;

    // stage D (32 j-rows): word = r*128 + (c ^ ((r&31)<<2))  [bijective in-row]
    const float4* Dg4 = (const float4*)(Dmat + (b * NN + jt * 32) * FI);
    #pragma unroll
    for (int k = 0; k < 2; ++k) {
        int s = tid + k * 512;
        float4 v = Dg4[s];
        int r = s >> 5, c = (s & 31) * 4;
        *(float4*)(sD + r * 128 + (c ^ ((r & 31) << 2))) = v;
    }
    // stage A (32 i-rows)
    const float4* Ag4 = (const float4*)(Ain + (b * NN + ir * 32) * FI);
    #pragma unroll
    for (int k = 0; k < 2; ++k) {
        int s = tid + k * 512;
        float4 v = Ag4[s];
        int r = s >> 5, c = (s & 31) * 4;
        *(float4*)(sA + r * 128 + (c ^ ((r & 31) << 2))) = v;
    }
    if (tid < 128) ((float4*)sC)[tid] = ((const float4*)coef)[tid];
    if (tid < 32) smax[tid] = 0;   // 0.0f == exact value of suppressed edges
    if (tid == 0) scnt = 0;
    __syncthreads();

    // compaction: 1024 candidates in 2 rounds; entries j-contiguous per i-row
    const float* S = sup + (size_t)(b * NN + ir * 32) * NN + jt * 32;
    #pragma unroll
    for (int k = 0; k < 2; ++k) {
        int s = tid + k * 512;
        int i_l = s >> 5, j_l = s & 31;
        bool act = (S[i_l * NN + j_l] != 0.f);
        unsigned long long mask = __ballot(act);
        int wbase = 0;
        if (lane == 0 && mask) wbase = atomicAdd(&scnt, (int)__popcll(mask));
        wbase = __shfl(wbase, 0);
        if (act) {
            int prefix = (int)__popcll(mask & ((1ull << lane) - 1ull));
            sList[wbase + prefix] = (unsigned short)s;
        }
    }
    __syncthreads();

    int cnt = scnt;
    float be2 = *be2p;
    const float2* pos2 = (const float2*)pos;

    for (int r = tid; r < cnt; r += 512) {
        int e = (int)sList[r];
        int i_l = e >> 5, j_l = e & 31;
        float2 pp = pos2[(size_t)(b * NN + ir * 32 + i_l) * NN + jt * 32 + j_l];
        const float* Ar = sA + i_l * 128;
        const float* Dr = sD + j_l * 128;
        int aswz = i_l << 2;           // i_l < 32
        int dswz = j_l << 2;           // j_l < 32
        float z = 0.f;
        #pragma unroll 4
        for (int gq = 0; gq < 32; ++gq) {
            float4 a  = *(const float4*)(Ar + ((gq * 4) ^ aswz));
            float4 d  = *(const float4*)(Dr + ((gq * 4) ^ dswz));
            float4 w0 = *(const float4*)(sC + gq * 16);
            float4 w1 = *(const float4*)(sC + gq * 16 + 4);
            float4 vv = *(const float4*)(sC + gq * 16 + 8);
            float y0 = __fmaf_rn(w1.x, pp.y, __fmaf_rn(w0.x, pp.x, a.x + d.x));
            float y1 = __fmaf_rn(w1.y, pp.y, __fmaf_rn(w0.y, pp.x, a.y + d.y));
            float y2 = __fmaf_rn(w1.z, pp.y, __fmaf_rn(w0.z, pp.x, a.z + d.z));
            float y3 = __fmaf_rn(w1.w, pp.y, __fmaf_rn(w0.w, pp.x, a.w + d.w));
            z = __fmaf_rn(vv.x, fast_gelu(y0), z);
            z = __fmaf_rn(vv.y, fast_gelu(y1), z);
            z = __fmaf_rn(vv.z, fast_gelu(y2), z);
            z = __fmaf_rn(vv.w, fast_gelu(y3), z);
        }
        // positive floats order-preserve as signed ints; negatives < 0 == init
        atomicMax(&smax[j_l], __float_as_int(z + be2));
    }
    __syncthreads();
    if (tid < 32)
        part[tile * 32 + tid] = __int_as_float(smax[tid]);
}

// ---- kernel 3: reduce 16 i-range partials + node FFN ------------------------
__global__ __launch_bounds__(256) void final_kernel(
    const float* __restrict__ Wn1, const float* __restrict__ bn1,
    const float* __restrict__ Wn2, const float* __restrict__ bn2,
    const float* __restrict__ part, float* __restrict__ out)
{
    __shared__ float red[8][17];
    __shared__ float nm[8];
    __shared__ __align__(16) float h1[8][FD];
    int nb = blockIdx.x * 8;                  // 256 blocks * 8 nodes
    int b  = nb >> 9;
    int j0 = nb & 511;
    int jt = j0 >> 5, jl0 = j0 & 31;          // 8-aligned j0 stays in one jt
    int t = threadIdx.x;
    if (t < 128) {
        int k = t & 7, ir = t >> 3;           // ir in 0..15
        red[k][ir] = part[(((b * 16 + jt) * 16) + ir) * 32 + jl0 + k];
    }
    __syncthreads();
    if (t < 8) {
        float m2 = red[t][0];
        #pragma unroll
        for (int q = 1; q < 16; ++q) m2 = fmaxf(m2, red[t][q]);
        nm[t] = m2;
    }
    __syncthreads();
    {
        float wv = Wn1[t];        // Wn1 shape [256,1]
        float bv = bn1[t];
        #pragma unroll
        for (int n = 0; n < 8; ++n)
            h1[n][t] = fmaxf(0.f, __fmaf_rn(nm[n], wv, bv));
    }
    __syncthreads();
    float acc[8] = {0.f,0.f,0.f,0.f,0.f,0.f,0.f,0.f};
    const float4* w2 = (const float4*)(Wn2 + t * FD);
    for (int d4 = 0; d4 < FD / 4; ++d4) {
        float4 wv = w2[d4];
        #pragma unroll
        for (int n = 0; n < 8; ++n) {
            float4 xv = ((const float4*)&h1[n][0])[d4];
            acc[n] = __fmaf_rn(wv.x, xv.x, acc[n]);
            acc[n] = __fmaf_rn(wv.y, xv.y, acc[n]);
            acc[n] = __fmaf_rn(wv.z, xv.z, acc[n]);
            acc[n] = __fmaf_rn(wv.w, xv.w, acc[n]);
        }
    }
    float bb = bn2[t];
    #pragma unroll
    for (int n = 0; n < 8; ++n)
        out[(size_t)(nb + n) * FD + t] = fmaxf(0.f, acc[n] + bb);
}

extern "C" void kernel_launch(void* const* d_in, const int* in_sizes, int n_in,
                              void* d_out, int out_size, void* d_ws, size_t ws_size,
                              hipStream_t stream) {
    (void)in_sizes; (void)n_in; (void)out_size; (void)ws_size;
    const float* node = (const float*)d_in[0];
    const float* sup  = (const float*)d_in[1];
    const float* pos  = (const float*)d_in[2];
    const float* Wp   = (const float*)d_in[3];
    const float* bp   = (const float*)d_in[4];
    const float* Wi   = (const float*)d_in[5];
    const float* bi   = (const float*)d_in[6];
    const float* Wo   = (const float*)d_in[7];
    const float* bo   = (const float*)d_in[8];
    const float* We1  = (const float*)d_in[9];
    const float* be1  = (const float*)d_in[10];
    const float* We2  = (const float*)d_in[11];
    const float* be2  = (const float*)d_in[12];
    const float* Wn1  = (const float*)d_in[13];
    const float* bn1  = (const float*)d_in[14];
    const float* Wn2  = (const float*)d_in[15];
    const float* bn2  = (const float*)d_in[16];
    float* ws  = (float*)d_ws;
    float* out = (float*)d_out;

    node_fused_kernel<<<512, 256, 0, stream>>>(node, Wp, bp, Wi, bi, Wo, bo,
                                               We1, be1, We2, ws);
    edge_kernel<<<1024, 512, 0, stream>>>(pos, sup, ws + OFF_AIN, ws + OFF_D,
                                          ws + OFF_COEF, be2, ws + OFF_PART);
    final_kernel<<<256, 256, 0, stream>>>(Wn1, bn1, Wn2, bn2,
                                          ws + OFF_PART, out);
}